// Round 1
// baseline (705.801 us; speedup 1.0000x reference)
//
#include <hip/hip_runtime.h>

#define NN 25000
#define NE 400000
#define TT 4
#define NDIM 128
#define EDIM 64
#define NO 32
#define EO 64
#define DD 128
#define OUTD 128

// ws offsets (in floats)
#define OFF_Z      0
#define OFF_ASRC   800000
#define OFF_BSRC   825000
#define OFF_BDST   850000
#define OFF_C1     875000
#define OFF_C2     1275000
#define OFF_S1X    1675000
#define OFF_GAMMA  2075000
#define OFF_S2X    2475000
#define OFF_ALPHA  2875000
#define OFF_M1     3275000
#define OFF_DEN1   3300000
#define OFF_M2     3325000
#define OFF_DEN2   3350000
#define OFF_ZPHI   3375000
#define OFF_BETA   3375512
#define OFF_HBETA  3376000
#define WS_FLOATS  6576000

__device__ __forceinline__ unsigned f2o(float f) {
    unsigned u = __float_as_uint(f);
    return (u & 0x80000000u) ? ~u : (u | 0x80000000u);
}
__device__ __forceinline__ float o2f(unsigned o) {
    unsigned u = (o & 0x80000000u) ? (o & 0x7fffffffu) : ~o;
    return __uint_as_float(u);
}
__device__ __forceinline__ float lrelu(float x) { return x > 0.f ? x : 0.01f * x; }

// ---- K1: z = nf @ W_n ; per-node scalars a_src, b_src, b_dst ----
__global__ __launch_bounds__(256) void k_node(const float* __restrict__ nf,
    const float* __restrict__ W_n, const float* __restrict__ w_eattn,
    const float* __restrict__ w_attn, float* __restrict__ z,
    float* __restrict__ a_src, float* __restrict__ b_src, float* __restrict__ b_dst)
{
    __shared__ float Wl[128 * 32];
    __shared__ float nl[8 * 128];
    int tid = threadIdx.x;
    for (int i = tid; i < 128 * 32 / 4; i += 256)
        ((float4*)Wl)[i] = ((const float4*)W_n)[i];
    int nb = blockIdx.x * 8;
    ((float4*)nl)[tid] = ((const float4*)(nf + (size_t)nb * 128))[tid];
    __syncthreads();
    int node = tid >> 5;
    int col = tid & 31;
    float acc = 0.f;
    #pragma unroll 8
    for (int k = 0; k < 128; ++k)
        acc += nl[node * 128 + k] * Wl[k * 32 + col];
    int n = nb + node;
    z[(size_t)n * 32 + col] = acc;
    float va = acc * w_eattn[64 + col];
    float vb = acc * w_attn[col];
    float vc = acc * w_attn[96 + col];
    #pragma unroll
    for (int m = 16; m >= 1; m >>= 1) {
        va += __shfl_xor(va, m);
        vb += __shfl_xor(vb, m);
        vc += __shfl_xor(vc, m);
    }
    if (col == 0) { a_src[n] = va; b_src[n] = vb; b_dst[n] = vc; }
}

// ---- K2: e_ft = ef @ W_e (written to out e_w region); c1, c2 ----
__global__ __launch_bounds__(256) void k_edge(const float* __restrict__ ef,
    const float* __restrict__ W_e, const float* __restrict__ w_eattn,
    const float* __restrict__ w_attn, float* __restrict__ eft_out,
    float* __restrict__ c1, float* __restrict__ c2)
{
    __shared__ float Wl[64 * 64];
    __shared__ float el[16 * 65];
    int tid = threadIdx.x;
    for (int i = tid; i < 64 * 64 / 4; i += 256)
        ((float4*)Wl)[i] = ((const float4*)W_e)[i];
    size_t eb = (size_t)blockIdx.x * 16;
    {
        float4 v = ((const float4*)(ef + eb * 64))[tid];
        int r = (tid * 4) / 64, k0 = (tid * 4) % 64;
        el[r * 65 + k0] = v.x; el[r * 65 + k0 + 1] = v.y;
        el[r * 65 + k0 + 2] = v.z; el[r * 65 + k0 + 3] = v.w;
    }
    __syncthreads();
    int ein = tid >> 4;
    int c0 = (tid & 15) * 4;
    float a0 = 0, a1 = 0, a2 = 0, a3 = 0;
    #pragma unroll 4
    for (int k = 0; k < 64; ++k) {
        float a = el[ein * 65 + k];
        const float* wr = &Wl[k * 64 + c0];
        a0 += a * wr[0]; a1 += a * wr[1]; a2 += a * wr[2]; a3 += a * wr[3];
    }
    size_t e = eb + ein;
    float4 o; o.x = a0; o.y = a1; o.z = a2; o.w = a3;
    ((float4*)(eft_out + e * 64))[c0 >> 2] = o;
    float p1 = a0 * w_eattn[c0] + a1 * w_eattn[c0 + 1] + a2 * w_eattn[c0 + 2] + a3 * w_eattn[c0 + 3];
    float p2 = a0 * w_attn[32 + c0] + a1 * w_attn[33 + c0] + a2 * w_attn[34 + c0] + a3 * w_attn[35 + c0];
    #pragma unroll
    for (int m = 8; m >= 1; m >>= 1) {
        p1 += __shfl_xor(p1, m);
        p2 += __shfl_xor(p2, m);
    }
    if ((tid & 15) == 0) { c1[e] = p1; c2[e] = p2; }
}

// ---- K3: s1 + segment max over src ----
__global__ void k_s1(const float* __restrict__ c1, const float* __restrict__ a_src,
                     const int* __restrict__ src, float* __restrict__ s1x, unsigned* __restrict__ m1)
{
    int e = blockIdx.x * 256 + threadIdx.x;
    if (e >= NE) return;
    int s = src[e];
    float v = lrelu(c1[e] + a_src[s]);
    s1x[e] = v;
    atomicMax(&m1[s], f2o(v));
}

// ---- K4: ex1 = exp(s1-m1); den1 += ----
__global__ void k_ex1(const int* __restrict__ src, float* __restrict__ s1x,
                      const unsigned* __restrict__ m1, float* __restrict__ den1)
{
    int e = blockIdx.x * 256 + threadIdx.x;
    if (e >= NE) return;
    int s = src[e];
    float ex = expf(s1x[e] - o2f(m1[s]));
    s1x[e] = ex;
    atomicAdd(&den1[s], ex);
}

// ---- K5: gamma; s2; segment max over dst ----
__global__ void k_gamma_s2(const int* __restrict__ src, const int* __restrict__ dst,
    const float* __restrict__ s1x, const float* __restrict__ den1,
    const float* __restrict__ c2, const float* __restrict__ b_src, const float* __restrict__ b_dst,
    float* __restrict__ gamma, float* __restrict__ s2x, unsigned* __restrict__ m2)
{
    int e = blockIdx.x * 256 + threadIdx.x;
    if (e >= NE) return;
    int s = src[e], t = dst[e];
    float g = s1x[e] / den1[s];
    gamma[e] = g;
    float v = lrelu(b_src[s] + g * c2[e] + b_dst[t]);
    s2x[e] = v;
    atomicMax(&m2[t], f2o(v));
}

// ---- K5b: e_w *= gamma (in place on out region) ----
__global__ void k_scale_ew(float* __restrict__ ew, const float* __restrict__ gamma)
{
    size_t total = (size_t)NE * 16;  // float4 count
    size_t stride = (size_t)gridDim.x * 256;
    for (size_t i = (size_t)blockIdx.x * 256 + threadIdx.x; i < total; i += stride) {
        size_t e = i >> 4;
        float g = gamma[e];
        float4 v = ((float4*)ew)[i];
        v.x *= g; v.y *= g; v.z *= g; v.w *= g;
        ((float4*)ew)[i] = v;
    }
}

// ---- K6: ex2 = exp(s2-m2); den2 += ----
__global__ void k_ex2(const int* __restrict__ dst, float* __restrict__ s2x,
                      const unsigned* __restrict__ m2, float* __restrict__ den2)
{
    int e = blockIdx.x * 256 + threadIdx.x;
    if (e >= NE) return;
    int t = dst[e];
    float ex = expf(s2x[e] - o2f(m2[t]));
    s2x[e] = ex;
    atomicAdd(&den2[t], ex);
}

// ---- K7: alpha store + zphi per-type global reduction ----
__global__ __launch_bounds__(256) void k_zphi(const int* __restrict__ src, const int* __restrict__ dst,
    const int* __restrict__ ety, const float* __restrict__ s2x, const float* __restrict__ den2,
    const float* __restrict__ z, const float* __restrict__ ew,
    float* __restrict__ alpha, float* __restrict__ zphi)
{
    __shared__ float zl[512];
    int tid = threadIdx.x;
    zl[tid] = 0.f; zl[tid + 256] = 0.f;
    __syncthreads();
    float acc0 = 0, acc1 = 0, acc2 = 0, acc3 = 0;
    long stride = (long)gridDim.x * 256;
    long gid0 = (long)blockIdx.x * 256 + tid;
    int d = (int)(gid0 & 127);
    for (long slot = gid0; slot < (long)NE * 128; slot += stride) {
        int e = (int)(slot >> 7);
        int dn = dst[e];
        float al = s2x[e] / den2[dn];
        if (d == 0) alpha[e] = al;
        float md;
        if (d < 32) md = z[(size_t)src[e] * 32 + d];
        else if (d < 96) md = ew[(size_t)e * 64 + (d - 32)];
        else md = z[(size_t)dn * 32 + (d - 96)];
        float v = al * md;
        int t = ety[e];
        acc0 += (t == 0) ? v : 0.f;
        acc1 += (t == 1) ? v : 0.f;
        acc2 += (t == 2) ? v : 0.f;
        acc3 += (t == 3) ? v : 0.f;
    }
    atomicAdd(&zl[d], acc0);
    atomicAdd(&zl[128 + d], acc1);
    atomicAdd(&zl[256 + d], acc2);
    atomicAdd(&zl[384 + d], acc3);
    __syncthreads();
    atomicAdd(&zphi[tid], zl[tid]);
    atomicAdd(&zphi[tid + 256], zl[tid + 256]);
}

// ---- K8: beta = softmax(lrelu(zphi @ w_sem)) ----
__global__ __launch_bounds__(128) void k_beta(const float* __restrict__ zphi,
    const float* __restrict__ w_sem, float* __restrict__ beta)
{
    int tid = threadIdx.x;
    float w = w_sem[tid];
    float p0 = zphi[tid] * w, p1 = zphi[128 + tid] * w;
    float p2 = zphi[256 + tid] * w, p3 = zphi[384 + tid] * w;
    #pragma unroll
    for (int m = 32; m >= 1; m >>= 1) {
        p0 += __shfl_xor(p0, m); p1 += __shfl_xor(p1, m);
        p2 += __shfl_xor(p2, m); p3 += __shfl_xor(p3, m);
    }
    __shared__ float s[2][4];
    if ((tid & 63) == 0) {
        int w_ = tid >> 6;
        s[w_][0] = p0; s[w_][1] = p1; s[w_][2] = p2; s[w_][3] = p3;
    }
    __syncthreads();
    if (tid == 0) {
        float d0 = lrelu(s[0][0] + s[1][0]);
        float d1 = lrelu(s[0][1] + s[1][1]);
        float d2 = lrelu(s[0][2] + s[1][2]);
        float d3 = lrelu(s[0][3] + s[1][3]);
        float mx = fmaxf(fmaxf(d0, d1), fmaxf(d2, d3));
        float e0 = expf(d0 - mx), e1 = expf(d1 - mx), e2 = expf(d2 - mx), e3 = expf(d3 - mx);
        float inv = 1.f / (e0 + e1 + e2 + e3);
        beta[0] = e0 * inv; beta[1] = e1 * inv; beta[2] = e2 * inv; beta[3] = e3 * inv;
    }
}

// ---- K9: hbeta[dst] += alpha*beta[t]*msg (atomic scatter) ----
__global__ void k_scatter(const int* __restrict__ src, const int* __restrict__ dst,
    const int* __restrict__ ety, const float* __restrict__ alpha, const float* __restrict__ beta,
    const float* __restrict__ z, const float* __restrict__ ew, float* __restrict__ hbeta)
{
    long total = (long)NE * 128;
    long stride = (long)gridDim.x * 256;
    for (long slot = (long)blockIdx.x * 256 + threadIdx.x; slot < total; slot += stride) {
        int e = (int)(slot >> 7);
        int d = (int)(slot & 127);
        int dn = dst[e];
        float w = alpha[e] * beta[ety[e]];
        float md;
        if (d < 32) md = z[(size_t)src[e] * 32 + d];
        else if (d < 96) md = ew[(size_t)e * 64 + (d - 32)];
        else md = z[(size_t)dn * 32 + (d - 96)];
        atomicAdd(&hbeta[(size_t)dn * 128 + d], w * md);
    }
}

// ---- K10: Z = hbeta @ W_fc2 ----
__global__ __launch_bounds__(256) void k_fc(const float* __restrict__ hb,
    const float* __restrict__ W, float* __restrict__ Z)
{
    __shared__ float hl[32 * 132];
    __shared__ float Wl[128 * 64];
    int tid = threadIdx.x;
    int nb = blockIdx.x * 32;
    for (int i = tid; i < 1024; i += 256) {
        int row = i >> 5, kc = (i & 31) * 4;
        float4 v = make_float4(0.f, 0.f, 0.f, 0.f);
        if (nb + row < NN) v = *(const float4*)&hb[(size_t)(nb + row) * 128 + kc];
        *(float4*)&hl[row * 132 + kc] = v;
    }
    for (int half = 0; half < 2; ++half) {
        __syncthreads();
        for (int i = tid; i < 2048; i += 256) {
            int k = i >> 4, c = (i & 15) * 4;
            *(float4*)&Wl[k * 64 + c] = *(const float4*)&W[(size_t)k * 128 + half * 64 + c];
        }
        __syncthreads();
        int node = tid >> 3;
        int c0 = (tid & 7) * 8;
        float acc[8] = {0, 0, 0, 0, 0, 0, 0, 0};
        #pragma unroll 4
        for (int k = 0; k < 128; ++k) {
            float a = hl[node * 132 + k];
            const float* wr = &Wl[k * 64 + c0];
            #pragma unroll
            for (int j = 0; j < 8; ++j) acc[j] += a * wr[j];
        }
        int n = nb + node;
        if (n < NN) {
            float4 o1, o2;
            o1.x = acc[0]; o1.y = acc[1]; o1.z = acc[2]; o1.w = acc[3];
            o2.x = acc[4]; o2.y = acc[5]; o2.z = acc[6]; o2.w = acc[7];
            *(float4*)&Z[(size_t)n * 128 + half * 64 + c0] = o1;
            *(float4*)&Z[(size_t)n * 128 + half * 64 + c0 + 4] = o2;
        }
    }
}

extern "C" void kernel_launch(void* const* d_in, const int* in_sizes, int n_in,
                              void* d_out, int out_size, void* d_ws, size_t ws_size,
                              hipStream_t stream)
{
    const float* nf     = (const float*)d_in[0];
    const float* ef     = (const float*)d_in[1];
    const int*   src    = (const int*)d_in[2];
    const int*   dst    = (const int*)d_in[3];
    const int*   ety    = (const int*)d_in[4];
    const float* W_n    = (const float*)d_in[5];
    const float* W_e    = (const float*)d_in[6];
    const float* w_eattn= (const float*)d_in[7];
    const float* w_attn = (const float*)d_in[8];
    const float* w_sem  = (const float*)d_in[9];
    const float* W_fc2  = (const float*)d_in[10];

    float* out = (float*)d_out;
    float* Z   = out;
    float* ew  = out + (size_t)NN * OUTD;

    float* ws    = (float*)d_ws;
    float* z     = ws + OFF_Z;
    float* a_src = ws + OFF_ASRC;
    float* b_src = ws + OFF_BSRC;
    float* b_dst = ws + OFF_BDST;
    float* c1    = ws + OFF_C1;
    float* c2    = ws + OFF_C2;
    float* s1x   = ws + OFF_S1X;
    float* gamma = ws + OFF_GAMMA;
    float* s2x   = ws + OFF_S2X;
    float* alpha = ws + OFF_ALPHA;
    unsigned* m1 = (unsigned*)(ws + OFF_M1);
    float* den1  = ws + OFF_DEN1;
    unsigned* m2 = (unsigned*)(ws + OFF_M2);
    float* den2  = ws + OFF_DEN2;
    float* zphi  = ws + OFF_ZPHI;
    float* beta  = ws + OFF_BETA;
    float* hbeta = ws + OFF_HBETA;

    // zero: m1, den1, m2, den2, zphi, beta, hbeta (contiguous)
    hipMemsetAsync(ws + OFF_M1, 0, (size_t)(WS_FLOATS - OFF_M1) * 4, stream);

    k_node<<<NN / 8, 256, 0, stream>>>(nf, W_n, w_eattn, w_attn, z, a_src, b_src, b_dst);
    k_edge<<<NE / 16, 256, 0, stream>>>(ef, W_e, w_eattn, w_attn, ew, c1, c2);
    int gE = (NE + 255) / 256;
    k_s1<<<gE, 256, 0, stream>>>(c1, a_src, src, s1x, m1);
    k_ex1<<<gE, 256, 0, stream>>>(src, s1x, m1, den1);
    k_gamma_s2<<<gE, 256, 0, stream>>>(src, dst, s1x, den1, c2, b_src, b_dst, gamma, s2x, m2);
    k_scale_ew<<<2048, 256, 0, stream>>>(ew, gamma);
    k_ex2<<<gE, 256, 0, stream>>>(dst, s2x, m2, den2);
    k_zphi<<<1024, 256, 0, stream>>>(src, dst, ety, s2x, den2, z, ew, alpha, zphi);
    k_beta<<<1, 128, 0, stream>>>(zphi, w_sem, beta);
    k_scatter<<<8192, 256, 0, stream>>>(src, dst, ety, alpha, beta, z, ew, hbeta);
    k_fc<<<(NN + 31) / 32, 256, 0, stream>>>(hbeta, W_fc2, Z);
}